// Round 8
// baseline (29.347 us; speedup 1.0000x reference)
//
#include <hip/hip_runtime.h>
#include <math.h>

#define LBL 16
#define B_TOTAL 32768
#define WAVES 8
#define BLOCK_THREADS (WAVES * 64)              // 512
#define COLS_PER_BLOCK 64
#define GRID_BLOCKS (B_TOTAL / COLS_PER_BLOCK)  // 512

// LDS u32-word offsets (main region 16448 words = 65792 B; part/wls separate,
// total ~76 KB -> still 2 blocks/CU, 4 waves/SIMD).
// [0,8192)       U: A1 fragment table, 1024 slots x 32B, permuted state->row
//                   (slot = half*512 + t*32 + q*16 + x; state o=16a+8b+4q+r -> x=8a+4b+r)
// [8192,16448)   scm: [l][pair ^ ((l&3)<<2)] u32, row stride 516 words (2064B)
#define SCM_WOFF 8192
#define SCM_STRIDE 516
#define LDS_WORDS (SCM_WOFF + LBL * SCM_STRIDE)   // 16448

typedef __attribute__((ext_vector_type(8))) short bf16x8;
typedef __attribute__((ext_vector_type(4))) float f32x4;

#define LOG2E 1.4426950408889634f

#if __has_builtin(__builtin_amdgcn_exp2f)
#define EXP2F __builtin_amdgcn_exp2f
#else
#define EXP2F exp2f
#endif

static __device__ __forceinline__ unsigned short bf16_rne(float x) {
    union { float f; unsigned u; } v; v.f = x;
    unsigned r = v.u + 0x7FFFu + ((v.u >> 16) & 1u);
    return (unsigned short)(r >> 16);
}
static __device__ __forceinline__ float bf16_to_f(unsigned short h) {
    union { unsigned u; float f; } v; v.u = ((unsigned)h) << 16;
    return v.f;
}
static __device__ __forceinline__ unsigned cvt_pk_bf16(float lo, float hi) {
    unsigned r;
    asm("v_cvt_pk_bf16_f32 %0, %1, %2" : "=v"(r) : "v"(lo), "v"(hi));
    return r;
}

#define PKB(p, q) ((((p) > 0) ? 0x3F80u : 0u) | (((q) > 0) ? 0x3F800000u : 0u))

__global__ __launch_bounds__(BLOCK_THREADS, 4) void plm_mfma7(
    const float* __restrict__ f, const float* __restrict__ y,
    const int* __restrict__ S, float* __restrict__ out,
    float* __restrict__ block_loss, unsigned* __restrict__ cnt)
{
    __shared__ __align__(16) unsigned SH[LDS_WORDS];
    __shared__ __align__(16) float part[WAVES * 16 * 20];  // [w][c][0..15]=num,[16]=z
    __shared__ float wls[WAVES];
    __shared__ int flag;
    unsigned short* U16 = (unsigned short*)SH;

    const int tid = threadIdx.x;

    // ---------------- Prologue: one thread : two consecutive states ----------------
    {
        const int s0 = tid * 2;
        int b0[16], b1[16];
        {
            const int4* sp = (const int4*)(S + (size_t)s0 * LBL);
            int4 a = sp[0], bq = sp[1], cq = sp[2], dq = sp[3];
            b0[0]=a.x;  b0[1]=a.y;  b0[2]=a.z;  b0[3]=a.w;
            b0[4]=bq.x; b0[5]=bq.y; b0[6]=bq.z; b0[7]=bq.w;
            b0[8]=cq.x; b0[9]=cq.y; b0[10]=cq.z;b0[11]=cq.w;
            b0[12]=dq.x;b0[13]=dq.y;b0[14]=dq.z;b0[15]=dq.w;
        }
        {
            const int4* sp = (const int4*)(S + (size_t)(s0 + 1) * LBL);
            int4 a = sp[0], bq = sp[1], cq = sp[2], dq = sp[3];
            b1[0]=a.x;  b1[1]=a.y;  b1[2]=a.z;  b1[3]=a.w;
            b1[4]=bq.x; b1[5]=bq.y; b1[6]=bq.z; b1[7]=bq.w;
            b1[8]=cq.x; b1[9]=cq.y; b1[10]=cq.z;b1[11]=cq.w;
            b1[12]=dq.x;b1[13]=dq.y;b1[14]=dq.z;b1[15]=dq.w;
        }
        // Permuted slot: state o = 16a+8b+4q+r -> chunk q, row x = 8a+4b+r, so that
        // MFMA1's C-layout == MFMA2's B-layout (k == o) and P stays in registers.
        const int half_s = s0 >> 9, tt = (s0 >> 5) & 15, o = s0 & 31;
        const int q = (o >> 2) & 1;
        const int x = ((o >> 4) & 1) * 8 + ((o >> 3) & 1) * 4 + (o & 3);
        const int slot = half_s * 512 + tt * 32 + q * 16 + x;
        unsigned short* Urow = U16 + slot * 16;
        uint4 ua = { PKB(b0[0],b0[1]),  PKB(b0[2],b0[3]),  PKB(b0[4],b0[5]),  PKB(b0[6],b0[7]) };
        uint4 ub = { PKB(b0[8],b0[9]),  PKB(b0[10],b0[11]),PKB(b0[12],b0[13]),PKB(b0[14],b0[15]) };
        uint4 uc = { PKB(b1[0],b1[1]),  PKB(b1[2],b1[3]),  PKB(b1[4],b1[5]),  PKB(b1[6],b1[7]) };
        uint4 ud = { PKB(b1[8],b1[9]),  PKB(b1[10],b1[11]),PKB(b1[12],b1[13]),PKB(b1[14],b1[15]) };
        *(uint4*)&Urow[0]  = ua;
        *(uint4*)&Urow[8]  = ub;
        *(uint4*)&Urow[16] = uc;
        *(uint4*)&Urow[24] = ud;
#pragma unroll
        for (int l = 0; l < 16; ++l) {
            unsigned v = (((b0[l] > 0) ? 0x3F80u : 0u)) | (((b1[l] > 0) ? 0x3F800000u : 0u));
            SH[SCM_WOFF + l * SCM_STRIDE + ((unsigned)tid ^ ((unsigned)(l & 3) << 2))] = v;
        }
    }
    __syncthreads();

    // ---------------- Per-wave setup ----------------
    const int w = tid >> 6, lane = tid & 63;
    const int c = lane & 15;          // batch col within group / MFMA row index
    const int g = lane >> 4;          // lane group 0..3
    const int cg = w & 3;             // column group
    const int half = w >> 2;          // state half
    const int b = blockIdx.x * COLS_PER_BLOCK + cg * LBL + c;
    const int h = g & 1;              // label half for this lane's k-range
    const int hilo = g >> 1;          // 0: bf16 hi of f2, 1: residual lo

    const float4* fr = (const float4*)(f + (size_t)b * LBL + h * 8);
    float4 x0 = fr[0], x1 = fr[1];
    float xs[8] = { x0.x, x0.y, x0.z, x0.w, x1.x, x1.y, x1.z, x1.w };
#pragma unroll
    for (int j = 0; j < 8; ++j) xs[j] *= LOG2E;

    float up = 0.f;
#pragma unroll
    for (int j = 0; j < 8; ++j) up += fmaxf(xs[j], 0.f);
    const float U2 = up + __shfl_xor(up, 16);
    const float nUb = -U2;
    const f32x4 cin = { nUb, nUb, nUb, nUb };   // bias folded into MFMA1 C-in

    union { unsigned short s[8]; bf16x8 v; } b1u;
#pragma unroll
    for (int j = 0; j < 8; ++j) {
        unsigned short hb = bf16_rne(xs[j]);
        unsigned short lb = bf16_rne(xs[j] - bf16_to_f(hb));
        b1u.s[j] = (unsigned short)(hilo ? lb : hb);
    }
    const bf16x8 b1f = b1u.v;

    // all-ones A fragment (layout-invariant) for the z-accumulating MFMA
    union { unsigned u[4]; bf16x8 v; } onesA;
    onesA.u[0] = 0x3F803F80u; onesA.u[1] = 0x3F803F80u;
    onesA.u[2] = 0x3F803F80u; onesA.u[3] = 0x3F803F80u;

    const unsigned gc = (unsigned)(g ^ (c & 3));
    const char* baseA  = (const char*)SH + half * 16384 + 32 * c + 16 * h;
    const char* baseS2 = (const char*)SH + SCM_WOFF * 4 + 2064 * c + 1024 * half + 16 * gc;

    f32x4 cacc = 0.0f;
    f32x4 zvec = 0.0f;

    // ---- Main loop: 16 tiles x 32 states, all dataflow through registers ----
#pragma unroll
    for (int t = 0; t < 16; ++t) {
        const char* pa = baseA + t * 1024;
        bf16x8 A0 = *(const bf16x8*)(pa);          // chunk q=0 (permuted rows)
        bf16x8 A1 = *(const bf16x8*)(pa + 512);    // chunk q=1
        bf16x8 a2 = *(const bf16x8*)(baseS2 + t * 64);

        f32x4 pot0 = __builtin_amdgcn_mfma_f32_16x16x32_bf16(A0, b1f, cin, 0, 0, 0);
        f32x4 pot1 = __builtin_amdgcn_mfma_f32_16x16x32_bf16(A1, b1f, cin, 0, 0, 0);

        float e0 = EXP2F(pot0[0]), e1 = EXP2F(pot0[1]);
        float e2 = EXP2F(pot0[2]), e3 = EXP2F(pot0[3]);
        float e4 = EXP2F(pot1[0]), e5 = EXP2F(pot1[1]);
        float e6 = EXP2F(pot1[2]), e7 = EXP2F(pot1[3]);

        union { unsigned u[4]; bf16x8 v; } b2;
        b2.u[0] = cvt_pk_bf16(e0, e1);
        b2.u[1] = cvt_pk_bf16(e2, e3);
        b2.u[2] = cvt_pk_bf16(e4, e5);
        b2.u[3] = cvt_pk_bf16(e6, e7);

        cacc = __builtin_amdgcn_mfma_f32_16x16x32_bf16(a2, b2.v, cacc, 0, 0, 0);
        zvec = __builtin_amdgcn_mfma_f32_16x16x32_bf16(onesA.v, b2.v, zvec, 0, 0, 0);
    }

    // ---- Stash partials (separate LDS region; no pre-barrier needed) ----
    *(f32x4*)&part[(w * 16 + c) * 20 + 4 * g] = cacc;
    part[(w * 16 + c) * 20 + 16 + g] = zvec[0];   // all rows of ones*P identical
    __syncthreads();

    // ---- Merge halves, write pMargin, per-block loss ----
    {
        const int cg2 = tid >> 7;          // 0..3
        const int c2  = (tid >> 3) & 15;   // 0..15
        const int lp  = tid & 7;           // label pair
        const int w0 = cg2, w1 = cg2 + 4;
        const int bg = blockIdx.x * COLS_PER_BLOCK + cg2 * LBL + c2;

        const float z = part[(w0 * 16 + c2) * 20 + 16] + part[(w1 * 16 + c2) * 20 + 16];
        const float invz = 1.0f / z;

        const float2 yv = *(const float2*)(y + (size_t)bg * LBL + 2 * lp);
        float yr[2] = { yv.x, yv.y };
        float* prow = out + 1 + (size_t)bg * LBL + 2 * lp;

        float ls = 0.f;
#pragma unroll
        for (int r2 = 0; r2 < 2; ++r2) {
            const int l = 2 * lp + r2;
            float num = part[(w0 * 16 + c2) * 20 + l] + part[(w1 * 16 + c2) * 20 + l];
            float p = num * invz;
            prow[r2] = p;
            float gv = yr[r2];
            float fid = sqrtf(fmaf(p, gv, 1e-8f)) + sqrtf(fmaf(1.f - p, 1.f - gv, 1e-8f));
            float pt = fmaf(p, gv, (1.f - p) * (1.f - gv));
            float at = fmaf(0.75f, gv, 0.25f * (1.f - gv));
            float om = 1.f - pt;
            ls += (1.f - fid) * at * om * om;
        }
#pragma unroll
        for (int off = 32; off; off >>= 1) ls += __shfl_down(ls, off);
        if (lane == 0) wls[w] = ls;
    }
    __syncthreads();

    // ---- Fused deterministic loss finisher (single-kernel graph) ----
    // Trigger: (old & 511) == 511 fires exactly once per 512 adds, regardless of
    // cnt's initial (poisoned/accumulated) value -> no memset dispatch needed.
    if (tid == 0) {
        float t = 0.f;
#pragma unroll
        for (int i = 0; i < WAVES; ++i) t += wls[i];
        __hip_atomic_store(&block_loss[blockIdx.x], t, __ATOMIC_RELEASE, __HIP_MEMORY_SCOPE_AGENT);
        unsigned old = __hip_atomic_fetch_add(cnt, 1u, __ATOMIC_ACQ_REL, __HIP_MEMORY_SCOPE_AGENT);
        flag = ((old & 511u) == 511u) ? 1 : 0;
    }
    __syncthreads();
    if (flag && tid < 64) {
        float s = 0.f;
        for (int i = tid; i < GRID_BLOCKS; i += 64)
            s += __hip_atomic_load(&block_loss[i], __ATOMIC_RELAXED, __HIP_MEMORY_SCOPE_AGENT);
#pragma unroll
        for (int off = 32; off; off >>= 1) s += __shfl_down(s, off);
        if (tid == 0) out[0] = s * (1.0f / ((float)B_TOTAL * (float)LBL));
    }
}

extern "C" void kernel_launch(void* const* d_in, const int* in_sizes, int n_in,
                              void* d_out, int out_size, void* d_ws, size_t ws_size,
                              hipStream_t stream) {
    const float* f = (const float*)d_in[0];   // [B, 16]
    const float* y = (const float*)d_in[1];   // [B, 16]
    const int*   S = (const int*)d_in[2];     // [1024, 16]
    float* out = (float*)d_out;               // [0]=loss, [1..]=pMargin
    float* bl  = (float*)d_ws;                // 512 block partials
    unsigned* cnt = (unsigned*)((char*)d_ws + GRID_BLOCKS * sizeof(float));

    plm_mfma7<<<GRID_BLOCKS, BLOCK_THREADS, 0, stream>>>(f, y, S, out, bl, cnt);
}

// Round 9
// 16.146 us; speedup vs baseline: 1.8175x; 1.8175x over previous
//
#include <hip/hip_runtime.h>
#include <math.h>

#define LBL 16
#define B_TOTAL 32768
#define WAVES 16
#define BLOCK_THREADS 1024
#define COLS_PER_BLOCK 128
#define GRID_BLOCKS (B_TOTAL / COLS_PER_BLOCK)  // 256 = 1 block/CU

// LDS u32-word offsets (16448 words = 65792 B -> 1 block/CU with 16 waves).
// [0,8192)       U: A1 fragment table, 1024 slots x 32B, permuted state->row
//                   (slot = half*512 + t*32 + q*16 + x; state o=16a+8b+4q+r -> x=8a+4b+r)
// [8192,16448)   scm: [l][pair ^ ((l&3)<<2)] u32, row stride 516 words (2064B)
#define SCM_WOFF 8192
#define SCM_STRIDE 516
#define LDS_WORDS (SCM_WOFF + LBL * SCM_STRIDE)   // 16448

typedef __attribute__((ext_vector_type(8))) short bf16x8;
typedef __attribute__((ext_vector_type(4))) float f32x4;

#define LOG2E 1.4426950408889634f

#if __has_builtin(__builtin_amdgcn_exp2f)
#define EXP2F __builtin_amdgcn_exp2f
#else
#define EXP2F exp2f
#endif

static __device__ __forceinline__ unsigned short bf16_rne(float x) {
    union { float f; unsigned u; } v; v.f = x;
    unsigned r = v.u + 0x7FFFu + ((v.u >> 16) & 1u);
    return (unsigned short)(r >> 16);
}
static __device__ __forceinline__ float bf16_to_f(unsigned short h) {
    union { unsigned u; float f; } v; v.u = ((unsigned)h) << 16;
    return v.f;
}
static __device__ __forceinline__ unsigned cvt_pk_bf16(float lo, float hi) {
    unsigned r;
    asm("v_cvt_pk_bf16_f32 %0, %1, %2" : "=v"(r) : "v"(lo), "v"(hi));
    return r;
}

#define PKB(p, q) ((((p) > 0) ? 0x3F80u : 0u) | (((q) > 0) ? 0x3F800000u : 0u))

__global__ __launch_bounds__(BLOCK_THREADS, 4) void plm_mfma8(
    const float* __restrict__ f, const float* __restrict__ y,
    const int* __restrict__ S, float* __restrict__ out,
    float* __restrict__ block_loss)
{
    __shared__ __align__(16) unsigned SH[LDS_WORDS];
    __shared__ float wls[WAVES];
    unsigned short* U16 = (unsigned short*)SH;
    // post-main-loop overlay (U region dead after the loop): [w][16][20] floats
    float* part = (float*)SH;

    const int tid = threadIdx.x;

    // ---------------- Indices + EARLY f prefetch (latency hides under prologue) ----------------
    const int w = tid >> 6, lane = tid & 63;
    const int c = lane & 15;          // batch col within group / MFMA row index
    const int g = lane >> 4;          // lane group 0..3
    const int cg = w & 7;             // column group (8 groups x 16 cols = 128)
    const int half = w >> 3;          // state half
    const int b = blockIdx.x * COLS_PER_BLOCK + cg * LBL + c;
    const int h = g & 1;              // label half for this lane's k-range
    const int hilo = g >> 1;          // 0: bf16 hi of f2, 1: residual lo

    const float4* fr = (const float4*)(f + (size_t)b * LBL + h * 8);
    float4 x0 = fr[0], x1 = fr[1];    // issued now; consumed after the barrier

    // ---------------- Prologue: threads 0..511, one thread : two consecutive states ----------------
    if (tid < 512) {
        const int s0 = tid * 2;
        int b0[16], b1[16];
        {
            const int4* sp = (const int4*)(S + (size_t)s0 * LBL);
            int4 a = sp[0], bq = sp[1], cq = sp[2], dq = sp[3];
            b0[0]=a.x;  b0[1]=a.y;  b0[2]=a.z;  b0[3]=a.w;
            b0[4]=bq.x; b0[5]=bq.y; b0[6]=bq.z; b0[7]=bq.w;
            b0[8]=cq.x; b0[9]=cq.y; b0[10]=cq.z;b0[11]=cq.w;
            b0[12]=dq.x;b0[13]=dq.y;b0[14]=dq.z;b0[15]=dq.w;
        }
        {
            const int4* sp = (const int4*)(S + (size_t)(s0 + 1) * LBL);
            int4 a = sp[0], bq = sp[1], cq = sp[2], dq = sp[3];
            b1[0]=a.x;  b1[1]=a.y;  b1[2]=a.z;  b1[3]=a.w;
            b1[4]=bq.x; b1[5]=bq.y; b1[6]=bq.z; b1[7]=bq.w;
            b1[8]=cq.x; b1[9]=cq.y; b1[10]=cq.z;b1[11]=cq.w;
            b1[12]=dq.x;b1[13]=dq.y;b1[14]=dq.z;b1[15]=dq.w;
        }
        // Permuted slot: state o = 16a+8b+4q+r -> chunk q, row x = 8a+4b+r, so that
        // MFMA1's C-layout == MFMA2's B-layout (k == o) and P stays in registers.
        // (s0 even, s0+1: same q, x+1 -> consecutive 32B rows.)
        const int half_s = s0 >> 9, tt = (s0 >> 5) & 15, o = s0 & 31;
        const int q = (o >> 2) & 1;
        const int x = ((o >> 4) & 1) * 8 + ((o >> 3) & 1) * 4 + (o & 3);
        const int slot = half_s * 512 + tt * 32 + q * 16 + x;
        unsigned short* Urow = U16 + slot * 16;
        uint4 ua = { PKB(b0[0],b0[1]),  PKB(b0[2],b0[3]),  PKB(b0[4],b0[5]),  PKB(b0[6],b0[7]) };
        uint4 ub = { PKB(b0[8],b0[9]),  PKB(b0[10],b0[11]),PKB(b0[12],b0[13]),PKB(b0[14],b0[15]) };
        uint4 uc = { PKB(b1[0],b1[1]),  PKB(b1[2],b1[3]),  PKB(b1[4],b1[5]),  PKB(b1[6],b1[7]) };
        uint4 ud = { PKB(b1[8],b1[9]),  PKB(b1[10],b1[11]),PKB(b1[12],b1[13]),PKB(b1[14],b1[15]) };
        *(uint4*)&Urow[0]  = ua;
        *(uint4*)&Urow[8]  = ub;
        *(uint4*)&Urow[16] = uc;
        *(uint4*)&Urow[24] = ud;
#pragma unroll
        for (int l = 0; l < 16; ++l) {
            unsigned v = (((b0[l] > 0) ? 0x3F80u : 0u)) | (((b1[l] > 0) ? 0x3F800000u : 0u));
            SH[SCM_WOFF + l * SCM_STRIDE + ((unsigned)tid ^ ((unsigned)(l & 3) << 2))] = v;
        }
    }
    __syncthreads();

    // ---------------- Per-wave setup (f already in x0/x1) ----------------
    float xs[8] = { x0.x, x0.y, x0.z, x0.w, x1.x, x1.y, x1.z, x1.w };
#pragma unroll
    for (int j = 0; j < 8; ++j) xs[j] *= LOG2E;

    float up = 0.f;
#pragma unroll
    for (int j = 0; j < 8; ++j) up += fmaxf(xs[j], 0.f);
    const float U2 = up + __shfl_xor(up, 16);
    const float nUb = -U2;
    const f32x4 cin = { nUb, nUb, nUb, nUb };   // bias folded into MFMA1 C-in

    union { unsigned short s[8]; bf16x8 v; } b1u;
#pragma unroll
    for (int j = 0; j < 8; ++j) {
        unsigned short hb = bf16_rne(xs[j]);
        unsigned short lb = bf16_rne(xs[j] - bf16_to_f(hb));
        b1u.s[j] = (unsigned short)(hilo ? lb : hb);
    }
    const bf16x8 b1f = b1u.v;

    const unsigned gc = (unsigned)(g ^ (c & 3));
    const char* baseA  = (const char*)SH + half * 16384 + 32 * c + 16 * h;
    const char* baseS2 = (const char*)SH + SCM_WOFF * 4 + 2064 * c + 1024 * half + 16 * gc;

    f32x4 cacc = 0.0f;
    float zacc = 0.f;

    // ---- Main loop: 16 tiles x 32 states, all dataflow through registers.
    //      unroll 4 caps ds_read hoisting -> VGPR stays under the 128 cap. ----
#pragma unroll 4
    for (int t = 0; t < 16; ++t) {
        const char* pa = baseA + t * 1024;
        bf16x8 A0 = *(const bf16x8*)(pa);          // chunk q=0 (permuted rows)
        bf16x8 A1 = *(const bf16x8*)(pa + 512);    // chunk q=1
        bf16x8 a2 = *(const bf16x8*)(baseS2 + t * 64);

        f32x4 pot0 = __builtin_amdgcn_mfma_f32_16x16x32_bf16(A0, b1f, cin, 0, 0, 0);
        f32x4 pot1 = __builtin_amdgcn_mfma_f32_16x16x32_bf16(A1, b1f, cin, 0, 0, 0);

        float e0 = EXP2F(pot0[0]), e1 = EXP2F(pot0[1]);
        float e2 = EXP2F(pot0[2]), e3 = EXP2F(pot0[3]);
        float e4 = EXP2F(pot1[0]), e5 = EXP2F(pot1[1]);
        float e6 = EXP2F(pot1[2]), e7 = EXP2F(pot1[3]);
        zacc += ((e0 + e1) + (e2 + e3)) + ((e4 + e5) + (e6 + e7));

        // Producer lane == consumer lane: B2 fragment assembled in registers.
        union { unsigned u[4]; bf16x8 v; } b2;
        b2.u[0] = cvt_pk_bf16(e0, e1);
        b2.u[1] = cvt_pk_bf16(e2, e3);
        b2.u[2] = cvt_pk_bf16(e4, e5);
        b2.u[3] = cvt_pk_bf16(e6, e7);

        cacc = __builtin_amdgcn_mfma_f32_16x16x32_bf16(a2, b2.v, cacc, 0, 0, 0);
    }

    // ---- Stash partials into overlay (U region dead); barrier protects reuse ----
    __syncthreads();
    *(f32x4*)&part[(w * 16 + c) * 20 + 4 * g] = cacc;
    part[(w * 16 + c) * 20 + 16 + g] = zacc;
    __syncthreads();

    // ---- Merge halves, write pMargin, per-block loss ----
    {
        const int cg2 = tid >> 7;          // 0..7
        const int c2  = (tid >> 3) & 15;   // 0..15
        const int lp  = tid & 7;           // label pair
        const int w0 = cg2, w1 = cg2 + 8;  // halves of the same column group
        const int bg = blockIdx.x * COLS_PER_BLOCK + cg2 * LBL + c2;

        float z = 0.f;
#pragma unroll
        for (int gg = 0; gg < 4; ++gg)
            z += part[(w0 * 16 + c2) * 20 + 16 + gg] + part[(w1 * 16 + c2) * 20 + 16 + gg];
        const float invz = 1.0f / z;

        const float2 yv = *(const float2*)(y + (size_t)bg * LBL + 2 * lp);
        float yr[2] = { yv.x, yv.y };
        float* prow = out + 1 + (size_t)bg * LBL + 2 * lp;

        float ls = 0.f;
#pragma unroll
        for (int r2 = 0; r2 < 2; ++r2) {
            const int l = 2 * lp + r2;
            float num = part[(w0 * 16 + c2) * 20 + l] + part[(w1 * 16 + c2) * 20 + l];
            float p = num * invz;
            prow[r2] = p;
            float gv = yr[r2];
            float fid = sqrtf(fmaf(p, gv, 1e-8f)) + sqrtf(fmaf(1.f - p, 1.f - gv, 1e-8f));
            float pt = fmaf(p, gv, (1.f - p) * (1.f - gv));
            float at = fmaf(0.75f, gv, 0.25f * (1.f - gv));
            float om = 1.f - pt;
            ls += (1.f - fid) * at * om * om;
        }
#pragma unroll
        for (int off = 32; off; off >>= 1) ls += __shfl_down(ls, off);
        if (lane == 0) wls[w] = ls;
    }
    __syncthreads();
    if (tid == 0) {
        float t = 0.f;
#pragma unroll
        for (int i = 0; i < WAVES; ++i) t += wls[i];
        block_loss[blockIdx.x] = t;
    }
}

__global__ __launch_bounds__(256) void plm_reduce(
    const float* __restrict__ block_loss, int n, float* __restrict__ out)
{
    __shared__ float wsum[4];
    float s = 0.f;
    for (int i = threadIdx.x; i < n; i += 256) s += block_loss[i];
#pragma unroll
    for (int off = 32; off; off >>= 1) s += __shfl_down(s, off);
    const int wave = threadIdx.x >> 6;
    if ((threadIdx.x & 63) == 0) wsum[wave] = s;
    __syncthreads();
    if (threadIdx.x == 0) {
        float t = (wsum[0] + wsum[1]) + (wsum[2] + wsum[3]);
        out[0] = t * (1.0f / ((float)B_TOTAL * (float)LBL));
    }
}

extern "C" void kernel_launch(void* const* d_in, const int* in_sizes, int n_in,
                              void* d_out, int out_size, void* d_ws, size_t ws_size,
                              hipStream_t stream) {
    const float* f = (const float*)d_in[0];   // [B, 16]
    const float* y = (const float*)d_in[1];   // [B, 16]
    const int*   S = (const int*)d_in[2];     // [1024, 16]
    float* out = (float*)d_out;               // [0]=loss, [1..]=pMargin
    float* bl  = (float*)d_ws;                // 256 block partials

    plm_mfma8<<<GRID_BLOCKS, BLOCK_THREADS, 0, stream>>>(f, y, S, out, bl);
    plm_reduce<<<1, 256, 0, stream>>>(bl, GRID_BLOCKS, out);
}

// Round 10
// 15.748 us; speedup vs baseline: 1.8635x; 1.0253x over previous
//
#include <hip/hip_runtime.h>
#include <math.h>

#define LBL 16
#define B_TOTAL 32768
#define WAVES 16
#define BLOCK_THREADS 1024
#define COLS_PER_BLOCK 128
#define GRID_BLOCKS (B_TOTAL / COLS_PER_BLOCK)  // 256 = 1 block/CU

// LDS u32-word offsets (16448 words = 65792 B -> 1 block/CU with 16 waves).
// [0,8192)       U: A1 fragment table, 1024 slots x 32B, permuted state->row
//                   (slot = half*512 + t*32 + q*16 + x; state o=16a+8b+4q+r -> x=8a+4b+r)
// [8192,16448)   scm: [l][pair ^ ((l&3)<<2)] u32, row stride 516 words (2064B)
#define SCM_WOFF 8192
#define SCM_STRIDE 516
#define LDS_WORDS (SCM_WOFF + LBL * SCM_STRIDE)   // 16448

typedef __attribute__((ext_vector_type(8))) short bf16x8;
typedef __attribute__((ext_vector_type(4))) float f32x4;

#define LOG2E 1.4426950408889634f

#if __has_builtin(__builtin_amdgcn_exp2f)
#define EXP2F __builtin_amdgcn_exp2f
#else
#define EXP2F exp2f
#endif

static __device__ __forceinline__ unsigned short bf16_rne(float x) {
    union { float f; unsigned u; } v; v.f = x;
    unsigned r = v.u + 0x7FFFu + ((v.u >> 16) & 1u);
    return (unsigned short)(r >> 16);
}
static __device__ __forceinline__ float bf16_to_f(unsigned short h) {
    union { unsigned u; float f; } v; v.u = ((unsigned)h) << 16;
    return v.f;
}
static __device__ __forceinline__ unsigned cvt_pk_bf16(float lo, float hi) {
    unsigned r;
    asm("v_cvt_pk_bf16_f32 %0, %1, %2" : "=v"(r) : "v"(lo), "v"(hi));
    return r;
}

#define PKB(p, q) ((((p) > 0) ? 0x3F80u : 0u) | (((q) > 0) ? 0x3F800000u : 0u))

__global__ __launch_bounds__(BLOCK_THREADS, 4) void plm_mfma9(
    const float* __restrict__ f, const float* __restrict__ y,
    const int* __restrict__ S, float* __restrict__ out,
    float* __restrict__ block_loss)
{
    __shared__ __align__(16) unsigned SH[LDS_WORDS];
    __shared__ float wls[WAVES];
    unsigned short* U16 = (unsigned short*)SH;
    // post-main-loop overlay (U region dead after the loop): [w][16][20] floats
    float* part = (float*)SH;

    const int tid = threadIdx.x;

    // ---------------- Indices ----------------
    const int w = tid >> 6, lane = tid & 63;
    const int c = lane & 15;          // batch col within group / MFMA row index
    const int g = lane >> 4;          // lane group 0..3
    const int cg = w & 7;             // column group (8 groups x 16 cols = 128)
    const int half = w >> 3;          // state half
    const int b = blockIdx.x * COLS_PER_BLOCK + cg * LBL + c;
    const int h = g & 1;              // label half for this lane's k-range
    const int hilo = g >> 1;          // 0: bf16 hi of f2, 1: residual lo

    // Epilogue indices are tid-pure: prefetch y NOW so its HBM latency hides
    // under the whole kernel instead of stalling the post-barrier epilogue.
    const int cg2 = tid >> 7;          // 0..7
    const int c2  = (tid >> 3) & 15;   // 0..15
    const int lp  = tid & 7;           // label pair
    const int bg  = blockIdx.x * COLS_PER_BLOCK + cg2 * LBL + c2;
    const float2 yv = *(const float2*)(y + (size_t)bg * LBL + 2 * lp);

    // f prefetch (consumed after the prologue barrier)
    const float4* fr = (const float4*)(f + (size_t)b * LBL + h * 8);
    float4 x0 = fr[0], x1 = fr[1];

    // ---------------- Prologue: ONE state per thread (all 1024 threads) ----------------
    {
        const int s = tid;
        const int4* sp = (const int4*)(S + (size_t)s * LBL);
        int4 ra = sp[0], rb = sp[1], rc = sp[2], rd = sp[3];
        int bb[16] = { ra.x, ra.y, ra.z, ra.w, rb.x, rb.y, rb.z, rb.w,
                       rc.x, rc.y, rc.z, rc.w, rd.x, rd.y, rd.z, rd.w };

        // Permuted slot: state o = 16a+8b+4q+r -> chunk q, row x = 8a+4b+r, so that
        // MFMA1's C-layout == MFMA2's B-layout (k == o) and P stays in registers.
        const int half_s = s >> 9, tt = (s >> 5) & 15, o = s & 31;
        const int q = (o >> 2) & 1;
        const int x = ((o >> 4) & 1) * 8 + ((o >> 3) & 1) * 4 + (o & 3);
        const int slot = half_s * 512 + tt * 32 + q * 16 + x;
        unsigned short* Urow = U16 + slot * 16;
        uint4 ua = { PKB(bb[0],bb[1]),  PKB(bb[2],bb[3]),  PKB(bb[4],bb[5]),  PKB(bb[6],bb[7]) };
        uint4 ub = { PKB(bb[8],bb[9]),  PKB(bb[10],bb[11]),PKB(bb[12],bb[13]),PKB(bb[14],bb[15]) };
        *(uint4*)&Urow[0] = ua;
        *(uint4*)&Urow[8] = ub;

        // scm pair (states 2i, 2i+1) assembled via lane-pair mask exchange
        unsigned m = 0;
#pragma unroll
        for (int l = 0; l < 16; ++l) m |= (bb[l] > 0 ? 1u : 0u) << l;
        unsigned mo = (unsigned)__shfl_xor((int)m, 1);
        if (!(tid & 1)) {
            const unsigned pr = (unsigned)(tid >> 1);
#pragma unroll
            for (int l = 0; l < 16; ++l) {
                unsigned v = (((m  >> l) & 1u) ? 0x3F80u : 0u)
                           | (((mo >> l) & 1u) ? 0x3F800000u : 0u);
                SH[SCM_WOFF + l * SCM_STRIDE + (pr ^ ((unsigned)(l & 3) << 2))] = v;
            }
        }
    }
    __syncthreads();

    // ---------------- Per-wave setup (f already in x0/x1) ----------------
    float xs[8] = { x0.x, x0.y, x0.z, x0.w, x1.x, x1.y, x1.z, x1.w };
#pragma unroll
    for (int j = 0; j < 8; ++j) xs[j] *= LOG2E;

    float up = 0.f;
#pragma unroll
    for (int j = 0; j < 8; ++j) up += fmaxf(xs[j], 0.f);
    const float U2 = up + __shfl_xor(up, 16);
    const float nUb = -U2;
    const f32x4 cin = { nUb, nUb, nUb, nUb };   // bias folded into MFMA1 C-in

    union { unsigned short s[8]; bf16x8 v; } b1u;
#pragma unroll
    for (int j = 0; j < 8; ++j) {
        unsigned short hb = bf16_rne(xs[j]);
        unsigned short lb = bf16_rne(xs[j] - bf16_to_f(hb));
        b1u.s[j] = (unsigned short)(hilo ? lb : hb);
    }
    const bf16x8 b1f = b1u.v;

    const unsigned gc = (unsigned)(g ^ (c & 3));
    const char* baseA  = (const char*)SH + half * 16384 + 32 * c + 16 * h;
    const char* baseS2 = (const char*)SH + SCM_WOFF * 4 + 2064 * c + 1024 * half + 16 * gc;

    // ---- Main loop: TWO independent tile streams (t, t+8) for ILP/MLP;
    //      separate accumulators halve the MFMA2 dependency chain. ----
    f32x4 cacc0 = 0.0f, cacc1 = 0.0f;
    float zacc0 = 0.f, zacc1 = 0.f;

#pragma unroll 2
    for (int t = 0; t < 8; ++t) {
        const char* pa0 = baseA + t * 1024;
        const char* pa1 = baseA + (t + 8) * 1024;
        bf16x8 A00 = *(const bf16x8*)(pa0);
        bf16x8 A01 = *(const bf16x8*)(pa0 + 512);
        bf16x8 A10 = *(const bf16x8*)(pa1);
        bf16x8 A11 = *(const bf16x8*)(pa1 + 512);
        bf16x8 a20 = *(const bf16x8*)(baseS2 + t * 64);
        bf16x8 a21 = *(const bf16x8*)(baseS2 + (t + 8) * 64);

        f32x4 p00 = __builtin_amdgcn_mfma_f32_16x16x32_bf16(A00, b1f, cin, 0, 0, 0);
        f32x4 p01 = __builtin_amdgcn_mfma_f32_16x16x32_bf16(A01, b1f, cin, 0, 0, 0);
        f32x4 p10 = __builtin_amdgcn_mfma_f32_16x16x32_bf16(A10, b1f, cin, 0, 0, 0);
        f32x4 p11 = __builtin_amdgcn_mfma_f32_16x16x32_bf16(A11, b1f, cin, 0, 0, 0);

        float e0 = EXP2F(p00[0]), e1 = EXP2F(p00[1]);
        float e2 = EXP2F(p00[2]), e3 = EXP2F(p00[3]);
        float e4 = EXP2F(p01[0]), e5 = EXP2F(p01[1]);
        float e6 = EXP2F(p01[2]), e7 = EXP2F(p01[3]);
        float u0 = EXP2F(p10[0]), u1 = EXP2F(p10[1]);
        float u2 = EXP2F(p10[2]), u3 = EXP2F(p10[3]);
        float u4 = EXP2F(p11[0]), u5 = EXP2F(p11[1]);
        float u6 = EXP2F(p11[2]), u7 = EXP2F(p11[3]);

        zacc0 += ((e0 + e1) + (e2 + e3)) + ((e4 + e5) + (e6 + e7));
        zacc1 += ((u0 + u1) + (u2 + u3)) + ((u4 + u5) + (u6 + u7));

        union { unsigned u[4]; bf16x8 v; } b20, b21;
        b20.u[0] = cvt_pk_bf16(e0, e1);
        b20.u[1] = cvt_pk_bf16(e2, e3);
        b20.u[2] = cvt_pk_bf16(e4, e5);
        b20.u[3] = cvt_pk_bf16(e6, e7);
        b21.u[0] = cvt_pk_bf16(u0, u1);
        b21.u[1] = cvt_pk_bf16(u2, u3);
        b21.u[2] = cvt_pk_bf16(u4, u5);
        b21.u[3] = cvt_pk_bf16(u6, u7);

        cacc0 = __builtin_amdgcn_mfma_f32_16x16x32_bf16(a20, b20.v, cacc0, 0, 0, 0);
        cacc1 = __builtin_amdgcn_mfma_f32_16x16x32_bf16(a21, b21.v, cacc1, 0, 0, 0);
    }
    const f32x4 cacc = cacc0 + cacc1;
    const float zacc = zacc0 + zacc1;

    // ---- Stash partials into overlay (U region dead); barrier protects reuse ----
    __syncthreads();
    *(f32x4*)&part[(w * 16 + c) * 20 + 4 * g] = cacc;
    part[(w * 16 + c) * 20 + 16 + g] = zacc;
    __syncthreads();

    // ---- Merge halves, write pMargin, per-block loss ----
    {
        const int w0 = cg2, w1 = cg2 + 8;  // halves of the same column group

        float z = 0.f;
#pragma unroll
        for (int gg = 0; gg < 4; ++gg)
            z += part[(w0 * 16 + c2) * 20 + 16 + gg] + part[(w1 * 16 + c2) * 20 + 16 + gg];
        const float invz = 1.0f / z;

        float yr[2] = { yv.x, yv.y };
        float* prow = out + 1 + (size_t)bg * LBL + 2 * lp;

        float ls = 0.f;
#pragma unroll
        for (int r2 = 0; r2 < 2; ++r2) {
            const int l = 2 * lp + r2;
            float num = part[(w0 * 16 + c2) * 20 + l] + part[(w1 * 16 + c2) * 20 + l];
            float p = num * invz;
            prow[r2] = p;
            float gv = yr[r2];
            float fid = sqrtf(fmaf(p, gv, 1e-8f)) + sqrtf(fmaf(1.f - p, 1.f - gv, 1e-8f));
            float pt = fmaf(p, gv, (1.f - p) * (1.f - gv));
            float at = fmaf(0.75f, gv, 0.25f * (1.f - gv));
            float om = 1.f - pt;
            ls += (1.f - fid) * at * om * om;
        }
#pragma unroll
        for (int off = 32; off; off >>= 1) ls += __shfl_down(ls, off);
        if (lane == 0) wls[w] = ls;
    }
    __syncthreads();
    if (tid == 0) {
        float t = 0.f;
#pragma unroll
        for (int i = 0; i < WAVES; ++i) t += wls[i];
        block_loss[blockIdx.x] = t;
    }
}

__global__ __launch_bounds__(256) void plm_reduce(
    const float* __restrict__ block_loss, int n, float* __restrict__ out)
{
    __shared__ float wsum[4];
    float s = 0.f;
    for (int i = threadIdx.x; i < n; i += 256) s += block_loss[i];
#pragma unroll
    for (int off = 32; off; off >>= 1) s += __shfl_down(s, off);
    const int wave = threadIdx.x >> 6;
    if ((threadIdx.x & 63) == 0) wsum[wave] = s;
    __syncthreads();
    if (threadIdx.x == 0) {
        float t = (wsum[0] + wsum[1]) + (wsum[2] + wsum[3]);
        out[0] = t * (1.0f / ((float)B_TOTAL * (float)LBL));
    }
}

extern "C" void kernel_launch(void* const* d_in, const int* in_sizes, int n_in,
                              void* d_out, int out_size, void* d_ws, size_t ws_size,
                              hipStream_t stream) {
    const float* f = (const float*)d_in[0];   // [B, 16]
    const float* y = (const float*)d_in[1];   // [B, 16]
    const int*   S = (const int*)d_in[2];     // [1024, 16]
    float* out = (float*)d_out;               // [0]=loss, [1..]=pMargin
    float* bl  = (float*)d_ws;                // 256 block partials

    plm_mfma9<<<GRID_BLOCKS, BLOCK_THREADS, 0, stream>>>(f, y, S, out, bl);
    plm_reduce<<<1, 256, 0, stream>>>(bl, GRID_BLOCKS, out);
}

// Round 11
// 15.479 us; speedup vs baseline: 1.8959x; 1.0174x over previous
//
#include <hip/hip_runtime.h>
#include <math.h>

#define LBL 16
#define B_TOTAL 32768
#define WAVES 16
#define BLOCK_THREADS 1024
#define COLS_PER_BLOCK 128
#define GRID_BLOCKS (B_TOTAL / COLS_PER_BLOCK)  // 256 = 1 block/CU

// LDS byte offsets (static 100 KB -> 1 block/CU, 16 waves = 4 waves/SIMD).
// [0, 32768)        U:  A1 table [qt][t][xrow 0..31][k=label 0..15] bf16(bit),
//                       state o=tile-offset placed at row x = swap-bits2<->3(o)
// [32768, 98304)    A2: [qt][t][sh][row 0..31][k=state 0..15] bf16;
//                       rows 0..15 = labels, row 16 = ones (z-row), 17..31 = 0
// [98304, 102400)   smask: packed 16-bit state masks, 1024 u32
#define U_BOFF     0
#define A2_BOFF    32768
#define SMASK_BOFF 98304
#define LDS_BYTES  102400

typedef __attribute__((ext_vector_type(8)))  short bf16x8;
typedef __attribute__((ext_vector_type(4)))  float f32x4;
typedef __attribute__((ext_vector_type(16))) float f32x16;

#define LOG2E 1.4426950408889634f

#if __has_builtin(__builtin_amdgcn_exp2f)
#define EXP2F __builtin_amdgcn_exp2f
#else
#define EXP2F exp2f
#endif

static __device__ __forceinline__ unsigned short bf16_rne(float x) {
    union { float f; unsigned u; } v; v.f = x;
    unsigned r = v.u + 0x7FFFu + ((v.u >> 16) & 1u);
    return (unsigned short)(r >> 16);
}
static __device__ __forceinline__ float bf16_to_f(unsigned short h) {
    union { unsigned u; float f; } v; v.u = ((unsigned)h) << 16;
    return v.f;
}
static __device__ __forceinline__ unsigned cvt_pk_bf16(float lo, float hi) {
    unsigned r;
    asm("v_cvt_pk_bf16_f32 %0, %1, %2" : "=v"(r) : "v"(lo), "v"(hi));
    return r;
}

// pack bits l, l+1 of mask m as two bf16 (1.0/0.0) in one u32
#define PKB2(m, l) (((((m) >> (l)) & 1u) ? 0x3F80u : 0u) | ((((m) >> ((l) + 1)) & 1u) ? 0x3F800000u : 0u))
// pack bit r of masks a, b as two bf16 in one u32
#define PKR(a, b, r) (((((a) >> (r)) & 1u) ? 0x3F80u : 0u) | ((((b) >> (r)) & 1u) ? 0x3F800000u : 0u))

__global__ __launch_bounds__(BLOCK_THREADS, 4) void plm_mfma10(
    const float* __restrict__ f, const float* __restrict__ y,
    const int* __restrict__ S, float* __restrict__ out,
    float* __restrict__ block_loss)
{
    __shared__ __align__(16) unsigned char SHB[LDS_BYTES];
    __shared__ float wls[WAVES];
    unsigned* SH = (unsigned*)SHB;

    const int tid = threadIdx.x;
    const int w = tid >> 6, lane = tid & 63;
    const int qt = w >> 2;            // state quarter (256 states)
    const int cg = w & 3;             // column group (32 cols)
    const int col = lane & 31;        // batch col within group == MFMA row index
    const int kh = lane >> 5;         // k-chunk half (0: k 0..7, 1: k 8..15)
    const int b = blockIdx.x * COLS_PER_BLOCK + cg * 32 + col;

    // Epilogue mapping is tid-pure: prefetch y now (latency hides under kernel)
    const int lp = tid & 7;            // label pair
    const int col128 = tid >> 3;       // 0..127
    const int bg = blockIdx.x * COLS_PER_BLOCK + col128;
    const float2 yv = *(const float2*)(y + (size_t)bg * LBL + 2 * lp);

    // f prefetch (consumed after prologue)
    const float4* fr = (const float4*)(f + (size_t)b * LBL + kh * 8);
    float4 fx0 = fr[0], fx1 = fr[1];

    // ---------------- Prologue phase A: thread = state s ----------------
    {
        const int s = tid;
        const int4* sp = (const int4*)(S + (size_t)s * LBL);
        int4 ra = sp[0], rb = sp[1], rc = sp[2], rd = sp[3];
        unsigned m = (ra.x>0?1u:0u)       | ((ra.y>0?1u:0u)<<1)  | ((ra.z>0?1u:0u)<<2)  | ((ra.w>0?1u:0u)<<3)
                   | ((rb.x>0?1u:0u)<<4)  | ((rb.y>0?1u:0u)<<5)  | ((rb.z>0?1u:0u)<<6)  | ((rb.w>0?1u:0u)<<7)
                   | ((rc.x>0?1u:0u)<<8)  | ((rc.y>0?1u:0u)<<9)  | ((rc.z>0?1u:0u)<<10) | ((rc.w>0?1u:0u)<<11)
                   | ((rd.x>0?1u:0u)<<12) | ((rd.y>0?1u:0u)<<13) | ((rd.z>0?1u:0u)<<14) | ((rd.w>0?1u:0u)<<15);
        // permuted row: x = o with bits 2 and 3 swapped -> C regs == B2 k-order
        const int qts = s >> 8, ts = (s >> 5) & 7, o = s & 31;
        const int x = (o & 3) | (((o >> 2) & 1) << 3) | (((o >> 3) & 1) << 2) | (o & 16);
        unsigned* Uw = SH + ((U_BOFF + qts * 8192 + ts * 1024 + x * 32) >> 2);
        uint4 w0 = { PKB2(m, 0), PKB2(m, 2),  PKB2(m, 4),  PKB2(m, 6)  };
        uint4 w1 = { PKB2(m, 8), PKB2(m, 10), PKB2(m, 12), PKB2(m, 14) };
        *(uint4*)Uw       = w0;
        *(uint4*)(Uw + 4) = w1;
        SH[(SMASK_BOFF >> 2) + s] = m;
    }
    __syncthreads();

    // ---------------- Prologue phase B: thread = (fragment, row-pair) ----------------
    {
        const int frag = tid >> 4;     // qt*16 + t*2 + sh; states = frag*16 .. +15
        const int rp = tid & 15;       // rows 2rp, 2rp+1
        const unsigned* mk = SH + (SMASK_BOFF >> 2) + frag * 16;
        uint4 q0 = *(const uint4*)(mk),     q1 = *(const uint4*)(mk + 4);
        uint4 q2 = *(const uint4*)(mk + 8), q3 = *(const uint4*)(mk + 12);
        unsigned mm[16] = { q0.x,q0.y,q0.z,q0.w, q1.x,q1.y,q1.z,q1.w,
                            q2.x,q2.y,q2.z,q2.w, q3.x,q3.y,q3.z,q3.w };
        unsigned* A2w = SH + ((A2_BOFF + frag * 1024 + rp * 64) >> 2);
#pragma unroll
        for (int rr = 0; rr < 2; ++rr) {
            const int r = rp * 2 + rr;
            uint4 lo, hi;
            if (r < 16) {              // label row: bit r of 16 states
                lo = (uint4){ PKR(mm[0],mm[1],r),   PKR(mm[2],mm[3],r),
                              PKR(mm[4],mm[5],r),   PKR(mm[6],mm[7],r) };
                hi = (uint4){ PKR(mm[8],mm[9],r),   PKR(mm[10],mm[11],r),
                              PKR(mm[12],mm[13],r), PKR(mm[14],mm[15],r) };
            } else if (r == 16) {      // z-row: all ones
                lo = (uint4){0x3F803F80u,0x3F803F80u,0x3F803F80u,0x3F803F80u};
                hi = lo;
            } else {                   // padding
                lo = (uint4){0u,0u,0u,0u};
                hi = lo;
            }
            *(uint4*)(A2w + rr * 8)     = lo;
            *(uint4*)(A2w + rr * 8 + 4) = hi;
        }
    }
    __syncthreads();

    // ---------------- Per-wave operands ----------------
    float xs[8] = { fx0.x, fx0.y, fx0.z, fx0.w, fx1.x, fx1.y, fx1.z, fx1.w };
#pragma unroll
    for (int j = 0; j < 8; ++j) xs[j] *= LOG2E;

    float up = 0.f;
#pragma unroll
    for (int j = 0; j < 8; ++j) up += fmaxf(xs[j], 0.f);
    const float U2 = up + __shfl_xor(up, 32);   // col partner is lane^32 now
    const float nUb = -U2;
    f32x16 cin;
#pragma unroll
    for (int j = 0; j < 16; ++j) cin[j] = nUb;  // bias folded into MFMA1 C-in

    union { unsigned short s[8]; bf16x8 v; } bhi, blo;
#pragma unroll
    for (int j = 0; j < 8; ++j) {
        unsigned short hb = bf16_rne(xs[j]);
        unsigned short lb = bf16_rne(xs[j] - bf16_to_f(hb));
        bhi.s[j] = hb; blo.s[j] = lb;
    }
    const bf16x8 b1hi = bhi.v, b1lo = blo.v;

    const char* pU  = (const char*)SHB + U_BOFF  + qt * 8192  + col * 32 + kh * 16;
    const char* pA2 = (const char*)SHB + A2_BOFF + qt * 16384 + col * 32 + kh * 16;

    f32x16 cacc = 0.0f;

    // ---- Main loop: 8 tiles x (32 states x 32 cols); P in registers throughout ----
#pragma unroll
    for (int t = 0; t < 8; ++t) {
        bf16x8 A1  = *(const bf16x8*)(pU + t * 1024);          // shared by hi+lo MFMA1
        bf16x8 A2a = *(const bf16x8*)(pA2 + t * 2048);         // states sh=0
        bf16x8 A2b = *(const bf16x8*)(pA2 + t * 2048 + 1024);  // states sh=1

        f32x16 pot = __builtin_amdgcn_mfma_f32_32x32x16_bf16(A1, b1lo, cin, 0, 0, 0);
        pot        = __builtin_amdgcn_mfma_f32_32x32x16_bf16(A1, b1hi, pot, 0, 0, 0);

        float e[16];
#pragma unroll
        for (int r = 0; r < 16; ++r) e[r] = EXP2F(pot[r]);

        // C regs -> B2 k-slots in ascending order (by the row permutation):
        // lane<32: regs 0..7 = states 0..7 (sh0 k), regs 8..15 = states 16..23 (sh1 k)
        // lane>=32: regs 0..7 = states 8..15,       regs 8..15 = states 24..31
        union { unsigned u[4]; bf16x8 v; } b2a, b2b;
        b2a.u[0] = cvt_pk_bf16(e[0], e[1]);   b2a.u[1] = cvt_pk_bf16(e[2], e[3]);
        b2a.u[2] = cvt_pk_bf16(e[4], e[5]);   b2a.u[3] = cvt_pk_bf16(e[6], e[7]);
        b2b.u[0] = cvt_pk_bf16(e[8], e[9]);   b2b.u[1] = cvt_pk_bf16(e[10], e[11]);
        b2b.u[2] = cvt_pk_bf16(e[12], e[13]); b2b.u[3] = cvt_pk_bf16(e[14], e[15]);

        cacc = __builtin_amdgcn_mfma_f32_32x32x16_bf16(A2a, b2a.v, cacc, 0, 0, 0);
        cacc = __builtin_amdgcn_mfma_f32_32x32x16_bf16(A2b, b2b.v, cacc, 0, 0, 0);
    }

    // ---- Stash partials (overlay U/A2 region; barrier first) ----
    // cacc rows: lane<32: regs0..3=labels0..3, regs4..7=labels8..11, reg8=z(row16)
    //            lane>=32: regs0..3=labels4..7, regs4..7=labels12..15
    __syncthreads();
    {
        float* pc = (float*)SHB + (w * 32 + col) * 20 + kh * 4;
        f32x4 v0 = { cacc[0], cacc[1], cacc[2], cacc[3] };
        f32x4 v1 = { cacc[4], cacc[5], cacc[6], cacc[7] };
        *(f32x4*)pc       = v0;
        *(f32x4*)(pc + 8) = v1;
        if (!kh) pc[16] = cacc[8];
    }
    __syncthreads();

    // ---- Merge quarters, write pMargin, per-block loss ----
    {
        const int cg2 = col128 >> 5, c32 = col128 & 31;
        const float* pp = (const float*)SHB;
        const int l0 = 2 * lp, l1 = l0 + 1;
        float z = 0.f, n0 = 0.f, n1 = 0.f;
#pragma unroll
        for (int q2 = 0; q2 < 4; ++q2) {
            const int base = ((q2 * 4 + cg2) * 32 + c32) * 20;
            z  += pp[base + 16];
            n0 += pp[base + l0];
            n1 += pp[base + l1];
        }
        const float invz = 1.0f / z;
        float* prow = out + 1 + (size_t)bg * LBL + 2 * lp;

        float nn[2] = { n0, n1 };
        float yr[2] = { yv.x, yv.y };
        float ls = 0.f;
#pragma unroll
        for (int r2 = 0; r2 < 2; ++r2) {
            float p = nn[r2] * invz;
            prow[r2] = p;
            float gv = yr[r2];
            float fid = sqrtf(fmaf(p, gv, 1e-8f)) + sqrtf(fmaf(1.f - p, 1.f - gv, 1e-8f));
            float pt = fmaf(p, gv, (1.f - p) * (1.f - gv));
            float at = fmaf(0.75f, gv, 0.25f * (1.f - gv));
            float om = 1.f - pt;
            ls += (1.f - fid) * at * om * om;
        }
#pragma unroll
        for (int off = 32; off; off >>= 1) ls += __shfl_down(ls, off);
        if (lane == 0) wls[w] = ls;
    }
    __syncthreads();
    if (tid == 0) {
        float t = 0.f;
#pragma unroll
        for (int i = 0; i < WAVES; ++i) t += wls[i];
        block_loss[blockIdx.x] = t;
    }
}

__global__ __launch_bounds__(256) void plm_reduce(
    const float* __restrict__ block_loss, int n, float* __restrict__ out)
{
    __shared__ float wsum[4];
    float s = 0.f;
    for (int i = threadIdx.x; i < n; i += 256) s += block_loss[i];
#pragma unroll
    for (int off = 32; off; off >>= 1) s += __shfl_down(s, off);
    const int wave = threadIdx.x >> 6;
    if ((threadIdx.x & 63) == 0) wsum[wave] = s;
    __syncthreads();
    if (threadIdx.x == 0) {
        float t = (wsum[0] + wsum[1]) + (wsum[2] + wsum[3]);
        out[0] = t * (1.0f / ((float)B_TOTAL * (float)LBL));
    }
}

extern "C" void kernel_launch(void* const* d_in, const int* in_sizes, int n_in,
                              void* d_out, int out_size, void* d_ws, size_t ws_size,
                              hipStream_t stream) {
    const float* f = (const float*)d_in[0];   // [B, 16]
    const float* y = (const float*)d_in[1];   // [B, 16]
    const int*   S = (const int*)d_in[2];     // [1024, 16]
    float* out = (float*)d_out;               // [0]=loss, [1..]=pMargin
    float* bl  = (float*)d_ws;                // 256 block partials

    plm_mfma10<<<GRID_BLOCKS, BLOCK_THREADS, 0, stream>>>(f, y, S, out, bl);
    plm_reduce<<<1, 256, 0, stream>>>(bl, GRID_BLOCKS, out);
}